// Round 12
// baseline (160.610 us; speedup 1.0000x reference)
//
#include <hip/hip_runtime.h>

// CapsuleBlock dynamic routing, MI355X — R12: W-in-registers b-loop.
// x: [64, 2048, 8] f32; W: [2048, 16, 8, 16] f32; out: [64, 16, 16] f32.
// R11 lesson: removing LDS from inner loop gained only 7us -> DS pipe wasn't
// the limiter. By elimination: W-load path (1024 scattered VMEM instrs/CU/pass,
// ~16K line-requests, fresh L2 latency per jj, 4 waves/SIMD can't hide).
// R12: wave owns ONE n, wf[8] loaded ONCE (32 VGPRs), loops 32 b's.
// W VMEM/CU/pass: 1024 -> 128 instrs, amortized. Squash hoisted into
// finalize kernels (q0 / q01 tables); partial 32MB (256-block reduce).

#define B_    64
#define NIN   2048
#define NW    4                     // waves per block = n's per block
#define BI    4                     // b's per iteration
#define NITER 8                     // iterations (32 b per block)
#define GXN   (NIN / NW)            // 512 n-chunks
#define GYB   (B_ / (BI * NITER))   // 2 b-groups
#define PBLK  (NITER * BI * 256)    // 8192 floats per block partial region

// v + dpp(v). CTRL: 0xB1 = quad_perm xor1, 0x4E = quad_perm xor2,
// 0x124 = row_ror:4, 0x128 = row_ror:8 (row = 16 lanes).
template<int CTRL>
__device__ __forceinline__ float dpp_add(float v) {
    int t = __builtin_amdgcn_update_dpp(0, __float_as_int(v), CTRL, 0xF, 0xF, true);
    return v + __int_as_float(t);
}

// MODE 0: partial += hat (per-n slice)   MODE 1: partial += softmax_k(hat.q)*hat
// q: precomputed ov table (q0 for pass1, q01=q0+squash(s1) for pass2).
template<int MODE>
__global__ __launch_bounds__(256) void k_pass(const float* __restrict__ x,
                                              const float* __restrict__ W,
                                              const float* __restrict__ q,
                                              float* __restrict__ partial) {
    __shared__ float4 red[NW][BI][64];     // 16 KB

    const int tid  = threadIdx.x;
    const int lane = tid & 63;
    const int w    = tid >> 6;
    const int k    = lane >> 2;
    const int o4   = lane & 3;
    const int n    = blockIdx.x * NW + w;
    const int bbase = blockIdx.y * (BI * NITER);

    // W fragment for this wave's single n: loaded ONCE, 32 VGPRs.
    const float* wp = W + ((size_t)n * 16 + k) * 128 + o4 * 4;
    float4 wf[8];
#pragma unroll
    for (int d = 0; d < 8; ++d) wf[d] = *(const float4*)(wp + d * 16);

    float* pblk = partial + (size_t)(blockIdx.y * GXN + blockIdx.x) * PBLK;

    for (int it = 0; it < NITER; ++it) {
        const int b0 = bbase + it * BI;

        // x scalars: wave-uniform addresses (n uniform per wave) -> SMEM path.
        const float* xp = x + ((size_t)b0 * NIN + n) * 8;
        float xs[BI][8];
#pragma unroll
        for (int i = 0; i < BI; ++i)
#pragma unroll
            for (int d = 0; d < 8; ++d)
                xs[i][d] = xp[(size_t)i * (NIN * 8) + d];

        float4 ovv[BI];
        if (MODE) {
#pragma unroll
            for (int i = 0; i < BI; ++i)
                ovv[i] = *(const float4*)&q[(b0 + i) * 256 + lane * 4];
        }

#pragma unroll
        for (int i = 0; i < BI; ++i) {
            float4 h = make_float4(0.f, 0.f, 0.f, 0.f);
#pragma unroll
            for (int d = 0; d < 8; ++d) {
                h.x = fmaf(xs[i][d], wf[d].x, h.x);
                h.y = fmaf(xs[i][d], wf[d].y, h.y);
                h.z = fmaf(xs[i][d], wf[d].z, h.z);
                h.w = fmaf(xs[i][d], wf[d].w, h.w);
            }
            if (MODE) {
                float part = h.x * ovv[i].x;
                part = fmaf(h.y, ovv[i].y, part);
                part = fmaf(h.z, ovv[i].z, part);
                part = fmaf(h.w, ovv[i].w, part);
                part = dpp_add<0xB1>(part);
                part = dpp_add<0x4E>(part);          // bias_k, quad-uniform
                // |bias| <~ 20 << 88: raw exp safe in f32 (validated R3-R11).
                float e = __expf(part);
                float es = e;
                es = dpp_add<0x124>(es);             // + ror4
                es = dpp_add<0x128>(es);             // -> sum of row's 4 k's
                es += __shfl_xor(es, 16);
                es += __shfl_xor(es, 32);            // full sum over 16 k's
                float c = __fdividef(e, es);
                h.x *= c; h.y *= c; h.z *= c; h.w *= c;
            }
            red[w][i][lane] = h;
        }
        __syncthreads();

        // Combine 4 waves (4 n's) -> contiguous 4 KB store for this b-quad.
        {
            int bl = tid >> 6, ln = tid & 63;
            float4 a  = red[0][bl][ln];
            float4 c1 = red[1][bl][ln];
            float4 c2 = red[2][bl][ln];
            float4 c3 = red[3][bl][ln];
            a.x += c1.x + c2.x + c3.x;
            a.y += c1.y + c2.y + c3.y;
            a.z += c1.z + c2.z + c3.z;
            a.w += c1.w + c2.w + c3.w;
            *(float4*)&pblk[(size_t)(it * BI + bl) * 256 + ln * 4] = a;
        }
        __syncthreads();                 // protect red[] reuse next iter
    }
}

// Sum 512 n-chunk slices per b, quartered: partial2[b][qq][256].
// partial[(by*GXN+bx)*PBLK + (it*BI+bl)*256 + t], b = by*32 + it*4 + bl.
__global__ __launch_bounds__(256) void k_reduce(const float* __restrict__ partial,
                                                float* __restrict__ partial2) {
    const int b  = blockIdx.x;           // 0..63
    const int qq = blockIdx.y;           // 0..3
    const int lane = threadIdx.x & 63;
    const int w    = threadIdx.x >> 6;
    const int by = b >> 5, bi = b & 31;
    const float* base = partial + (size_t)by * GXN * PBLK + (size_t)bi * 256 + lane * 4;
    const int bx0 = qq * 128 + w * 32;
    float4 a = make_float4(0.f, 0.f, 0.f, 0.f);
#pragma unroll 8
    for (int j = 0; j < 32; ++j) {
        float4 v = *(const float4*)(base + (size_t)(bx0 + j) * PBLK);
        a.x += v.x; a.y += v.y; a.z += v.z; a.w += v.w;
    }
    __shared__ float4 red[4][64];
    red[w][lane] = a;
    __syncthreads();
    if (w == 0) {
        float4 r1 = red[1][lane], r2 = red[2][lane], r3 = red[3][lane];
        a.x += r1.x + r2.x + r3.x;
        a.y += r1.y + r2.y + r3.y;
        a.z += r1.z + r2.z + r3.z;
        a.w += r1.w + r2.w + r3.w;
        *(float4*)&partial2[(size_t)((b << 2) + qq) * 256 + lane * 4] = a;
    }
}

// F=0: dst = squash(s/16) (=q0)   F=1: dst = q0 + squash(s) (=q01)
// F=2: dst = squash(s) (= final out). One wave per b.
template<int F>
__global__ __launch_bounds__(64) void k_fin(const float* __restrict__ partial2,
                                            const float* __restrict__ q0,
                                            float* __restrict__ dst) {
    const int b = blockIdx.x;
    const int lane = threadIdx.x;
    float4 a = make_float4(0.f, 0.f, 0.f, 0.f);
#pragma unroll
    for (int qq = 0; qq < 4; ++qq) {
        float4 v = *(const float4*)&partial2[(size_t)((b << 2) + qq) * 256 + lane * 4];
        a.x += v.x; a.y += v.y; a.z += v.z; a.w += v.w;
    }
    if (F == 0) { a.x *= 0.0625f; a.y *= 0.0625f; a.z *= 0.0625f; a.w *= 0.0625f; }
    float sq = a.x*a.x + a.y*a.y + a.z*a.z + a.w*a.w;
    sq = dpp_add<0xB1>(sq);
    sq = dpp_add<0x4E>(sq);                  // sum over this k-row's 16 o's
    float sc = sq / (1.f + sq) * rsqrtf(sq);
    float4 o = make_float4(a.x*sc, a.y*sc, a.z*sc, a.w*sc);
    if (F == 1) {
        float4 p = *(const float4*)&q0[b * 256 + lane * 4];
        o.x += p.x; o.y += p.y; o.z += p.z; o.w += p.w;
    }
    *(float4*)&dst[b * 256 + lane * 4] = o;
}

extern "C" void kernel_launch(void* const* d_in, const int* in_sizes, int n_in,
                              void* d_out, int out_size, void* d_ws, size_t ws_size,
                              hipStream_t stream) {
    const float* x = (const float*)d_in[0];
    const float* W = (const float*)d_in[1];
    float* out = (float*)d_out;

    float* q0  = (float*)d_ws;                    // [64][256]
    float* q01 = q0 + B_ * 256;                   // [64][256]
    float* partial2 = q01 + B_ * 256;             // [64][4][256] = 256 KB
    float* partial  = partial2 + B_ * 4 * 256;    // 1024 x 32 KB = 32 MB

    dim3 pgrid(GXN, GYB);                         // (512, 2) = 1024 blocks
    dim3 rgrid(B_, 4);                            // (64, 4)

    k_pass<0><<<pgrid, 256, 0, stream>>>(x, W, nullptr, partial);
    k_reduce<<<rgrid, 256, 0, stream>>>(partial, partial2);
    k_fin<0><<<B_, 64, 0, stream>>>(partial2, nullptr, q0);

    k_pass<1><<<pgrid, 256, 0, stream>>>(x, W, q0, partial);
    k_reduce<<<rgrid, 256, 0, stream>>>(partial, partial2);
    k_fin<1><<<B_, 64, 0, stream>>>(partial2, q0, q01);

    k_pass<1><<<pgrid, 256, 0, stream>>>(x, W, q01, partial);
    k_reduce<<<rgrid, 256, 0, stream>>>(partial, partial2);
    k_fin<2><<<B_, 64, 0, stream>>>(partial2, nullptr, out);
}